// Round 5
// baseline (140.640 us; speedup 1.0000x reference)
//
#include <hip/hip_runtime.h>
#include <stdint.h>

// ---------------------------------------------------------------------------
// SelfAttentiveBimodalFusion: MLP(192->16->16) -> Q(8),K(8),V(64) -> full
// N x N attention -> out (N,64).  N = 12288.  fp32 in / fp32 out.
// Validated r5-r14: absmax 9.8e-4 vs thr 2.7e-3.
//
// Ladder: r5 killed atomics, r9 global_load_lds DMA -> k2=50us, r10 query-
// split waves + bf16 partials -> 46us, r12 MFMA-ones denominator + 64-key
// iters at (256,4) -> 44us, r14 counted-vmcnt 4-deep pipeline -> ~43us
// (NEUTRAL: the stall was never the vmem drain).
// r11 FAILED: (256,6) caps unified VGPR+AGPR at 85/wave -> scratch spill.
// r13 FAILED: 128-thr blocks halved waves/SIMD -> 47.5us.
// r15 (this): scheduling geometry, not intra-block pipelining:
//   (a) GRID BALANCE: 96 q-blocks x S=16 = 1536 blocks over 1024-block
//       capacity (4 blocks/CU: LDS 4x40960B = exactly 160KiB) ran as
//       1024 + 512 -> the whole 2nd round at half machine = built-in 25%
//       loss.  S=32 -> 3072 blocks = exactly 3x1024 (or 4x768 if the
//       runtime reserves LDS and fits 3/CU) -> balanced either way.
//       Cost: po partials 25->50MB (+4us k3, write BW in k2 trivial).
//   (b) epilogue: 4 serialized wave-rounds / 8 barriers -> ONE barrier +
//       per-wave private scratch (4x8712B = 34848 <= 40960 union), each
//       wave reads only its own region (same-wave lgkm ordering, no
//       barriers; 2-way bank alias is free per m136).
// ---------------------------------------------------------------------------

#define NN 12288

typedef float    f32x16 __attribute__((ext_vector_type(16)));
typedef short    s16x8  __attribute__((ext_vector_type(8)));
typedef unsigned short u16;

#define MFMA_32x32x16_BF16 __builtin_amdgcn_mfma_f32_32x32x16_bf16

// ws layout (bytes)
#define OFF_QB   0u          // N*8*2 = 196608 (bf16 Q, pre-scaled)
#define OFF_VT   196608u     // 192 chunks * 10240 B = 1966080 (V 9216 + K 1024)
#define OFF_PO   2162688u    // S*N*64*2 bf16 O partials; pl follows (S*N*4 fp32)

// s_waitcnt imm: vm[3:0]=n, exp=7 (nowait), lgkm=0xF (nowait)
#define VMCNT(n) (0x0F70 | (n))

typedef __attribute__((address_space(3))) void lds_void_t;
typedef const __attribute__((address_space(1))) void gbl_void_t;
__device__ __forceinline__ void gld16(const void* g, void* l) {
    __builtin_amdgcn_global_load_lds((gbl_void_t*)g, (lds_void_t*)l, 16, 0, 0);
}

__device__ __forceinline__ float bf2f(u16 s) {
    union { unsigned int u; float f; } c; c.u = ((unsigned int)s) << 16; return c.f;
}
__device__ __forceinline__ u16 f2bf(float f) {
    union { float f; unsigned int u; } c; c.f = f;
    return (u16)((c.u + 0x8000u) >> 16);
}
__device__ __forceinline__ unsigned int pk2(float a, float b) {
    union { float f; unsigned int u; } ca, cb; ca.f = a; cb.f = b;
    return ((ca.u + 0x8000u) >> 16) | ((cb.u + 0x8000u) & 0xffff0000u);
}
__device__ __forceinline__ unsigned int pkbf(float a, float b) {
#if __has_builtin(__builtin_amdgcn_cvt_pk_bf16_f32)
    auto r = __builtin_amdgcn_cvt_pk_bf16_f32(a, b);
    union { decltype(r) v; unsigned int u; } c; c.v = r; return c.u;
#else
    return pk2(a, b);
#endif
}
__device__ __forceinline__ f32x16 zf16() {
    f32x16 z;
#pragma unroll
    for (int i = 0; i < 16; ++i) z[i] = 0.f;
    return z;
}
__device__ __forceinline__ s16x8 zs8() {
    s16x8 z;
#pragma unroll
    for (int i = 0; i < 8; ++i) z[i] = 0;
    return z;
}

union U8 { s16x8 v; unsigned int u[4]; };

// ---------------- kernel 1: detect + weights->LDS + MLP -> Qb, Vt(+K) ------
__global__ __launch_bounds__(256) void k1_qkv(
    const void* __restrict__ xmain, const void* __restrict__ xmod,
    const void* __restrict__ we1, const void* __restrict__ we2,
    const void* __restrict__ wqp, const void* __restrict__ wkp,
    const void* __restrict__ wvp,
    u16* __restrict__ qb, u16* __restrict__ vt)
{
    __shared__ float wf[4608];
    __shared__ int   sflag;
    __shared__ float lh1[64][4][17];
    __shared__ float lh2[64][17];

    const int t = threadIdx.x;
    const int r = t >> 2;
    const int p = t & 3;
    const int row = blockIdx.x * 64 + r;

    if (t == 0) sflag = 0;
    __syncthreads();
    {
        float v = bf2f(((const u16*)xmod)[2 * t]);
        if (fabsf(v) > 16.f) atomicAdd(&sflag, 1);
    }
    __syncthreads();
    const int isf32 = (sflag > 8);

    const float SCL = 0.51006979f;       // (1/sqrt(8)) * log2(e)
    if (isf32) {
        const float* a1 = (const float*)we1; const float* a2 = (const float*)we2;
        const float* aq = (const float*)wqp; const float* ak = (const float*)wkp;
        const float* av = (const float*)wvp;
        for (int i = t; i < 4608; i += 256) {
            if      (i < 3072) wf[i] = a1[i];
            else if (i < 3328) wf[i] = a2[i - 3072];
            else if (i < 3456) wf[i] = aq[i - 3328] * SCL;
            else if (i < 3584) wf[i] = ak[i - 3456];
            else               wf[i] = av[i - 3584];
        }
    } else {
        const u16* a1 = (const u16*)we1; const u16* a2 = (const u16*)we2;
        const u16* aq = (const u16*)wqp; const u16* ak = (const u16*)wkp;
        const u16* av = (const u16*)wvp;
        for (int i = t; i < 4608; i += 256) {
            if      (i < 3072) wf[i] = bf2f(a1[i]);
            else if (i < 3328) wf[i] = bf2f(a2[i - 3072]);
            else if (i < 3456) wf[i] = bf2f(aq[i - 3328]) * SCL;
            else if (i < 3584) wf[i] = bf2f(ak[i - 3456]);
            else               wf[i] = bf2f(av[i - 3584]);
        }
    }
    __syncthreads();

    const float* __restrict__ W1 = wf;
    const float* __restrict__ W2 = wf + 3072;
    const float* __restrict__ Wq = wf + 3328;
    const float* __restrict__ Wk = wf + 3456;
    const float* __restrict__ Wv = wf + 3584;

    float h1p[16];
#pragma unroll
    for (int o = 0; o < 16; ++o) h1p[o] = 0.f;

    if (isf32) {
#pragma unroll
        for (int cc = 0; cc < 12; ++cc) {
            const int c = p + cc * 4;
            float4 xv = (c < 16)
                ? ((const float4*)xmain)[(size_t)row * 16 + c]
                : ((const float4*)xmod)[(size_t)row * 32 + (c - 16)];
            float xs[4] = {xv.x, xv.y, xv.z, xv.w};
#pragma unroll
            for (int j = 0; j < 4; ++j) {
                const float* wr = W1 + (c * 4 + j) * 16;
#pragma unroll
                for (int o = 0; o < 16; ++o) h1p[o] += xs[j] * wr[o];
            }
        }
    } else {
#pragma unroll
        for (int cc = 0; cc < 12; ++cc) {
            const int c = p + cc * 4;
            uint2 xv = (c < 16)
                ? ((const uint2*)xmain)[(size_t)row * 16 + c]
                : ((const uint2*)xmod)[(size_t)row * 32 + (c - 16)];
            float xs[4] = { bf2f((u16)(xv.x & 0xffff)), bf2f((u16)(xv.x >> 16)),
                            bf2f((u16)(xv.y & 0xffff)), bf2f((u16)(xv.y >> 16)) };
#pragma unroll
            for (int j = 0; j < 4; ++j) {
                const float* wr = W1 + (c * 4 + j) * 16;
#pragma unroll
                for (int o = 0; o < 16; ++o) h1p[o] += xs[j] * wr[o];
            }
        }
    }
#pragma unroll
    for (int o = 0; o < 16; ++o) lh1[r][p][o] = h1p[o];
    __syncthreads();

    float h1[16];
#pragma unroll
    for (int o = 0; o < 16; ++o)
        h1[o] = fmaxf(lh1[r][0][o] + lh1[r][1][o] + lh1[r][2][o] + lh1[r][3][o], 0.f);

#pragma unroll
    for (int oo = 0; oo < 4; ++oo) {
        const int o = p * 4 + oo;
        float s = 0.f;
#pragma unroll
        for (int j = 0; j < 16; ++j) s += h1[j] * W2[j * 16 + o];
        lh2[r][o] = fmaxf(s, 0.f);
    }
    __syncthreads();

    float h2[16];
#pragma unroll
    for (int j = 0; j < 16; ++j) h2[j] = lh2[r][j];

    {
        float q0 = 0.f, q1 = 0.f, k0 = 0.f, k1 = 0.f;
        const int o = 2 * p;
#pragma unroll
        for (int j = 0; j < 16; ++j) {
            q0 += h2[j] * Wq[j * 8 + o];
            q1 += h2[j] * Wq[j * 8 + o + 1];
            k0 += h2[j] * Wk[j * 8 + o];
            k1 += h2[j] * Wk[j * 8 + o + 1];
        }
        ((unsigned int*)qb)[(size_t)row * 4 + p] = pk2(q0, q1);
        // K fragment into the chunk's K region (u32 units):
        // chunk = row>>6 (2560 u32 each), K base 2304, key row&63, word p
        ((unsigned int*)vt)[(size_t)(row >> 6) * 2560 + 2304 +
                            (row & 63) * 4 + p] = pk2(k0, k1);
    }

    // V store, chunk layout: [chunk][tile(2)][c][kk], row stride 36 u16 (72 B)
    const int ch = row >> 6, tI = (row >> 5) & 1, kk = row & 31;
#pragma unroll
    for (int c16 = 0; c16 < 16; ++c16) {
        const int c = p * 16 + c16;
        float v = 0.f;
#pragma unroll
        for (int j = 0; j < 16; ++j) v += h2[j] * Wv[j * 64 + c];
        vt[(size_t)ch * 5120 + tI * 2304 + c * 36 + kk] = f2bf(v);
    }
}

// --------------------------- kernel 2: attention partials -------------------
// grid = 96 q-blocks * S key-splits (S=32 -> 3072 = 3x1024 = 4x768, balanced
// for both 4- and 3-blocks/CU capacity); block = 256 thr = 4 waves x 32q.
// 64-key chunks (V 9216B + K 1024B) in a 4-stage LDS pipeline, 2 chunks in
// flight, counted vmcnt (never 0 in steady state), raw s_barrier.
// Register budget (r11/r13 lessons): VGPR+AGPR total must stay <= 128 for
// 4 waves/SIMD; acc0+acc1+accl = 48 AGPR + ~45 arch VGPR ~= 96.

__device__ __forceinline__ void tile_pv(
    const f32x16& S, const u16* __restrict__ base, int l31, int half,
    const s16x8& ones, f32x16& acc0, f32x16& acc1, f32x16& accl)
{
    float pr[16];
#pragma unroll
    for (int r = 0; r < 16; ++r) pr[r] = __builtin_amdgcn_exp2f(S[r]);

    U8 p0, p1;
#pragma unroll
    for (int i = 0; i < 4; ++i) {
        p0.u[i] = pkbf(pr[2 * i],     pr[2 * i + 1]);
        p1.u[i] = pkbf(pr[8 + 2 * i], pr[8 + 2 * i + 1]);
    }

    // denominator: every output row of MFMA(1, P) = sum_k P[k][q]
    accl = MFMA_32x32x16_BF16(ones, p0.v, accl, 0, 0, 0);
    accl = MFMA_32x32x16_BF16(ones, p1.v, accl, 0, 0, 0);

    const u16* r0 = base + l31 * 36 + 4 * half;          // channels 0..31
    const u16* r1 = base + (32 + l31) * 36 + 4 * half;   // channels 32..63
    U8 va;
    uint2 x0, x1;
    x0 = *(const uint2*)(r0);       x1 = *(const uint2*)(r0 + 8);
    va.u[0] = x0.x; va.u[1] = x0.y; va.u[2] = x1.x; va.u[3] = x1.y;
    acc0 = MFMA_32x32x16_BF16(va.v, p0.v, acc0, 0, 0, 0);
    x0 = *(const uint2*)(r1);       x1 = *(const uint2*)(r1 + 8);
    va.u[0] = x0.x; va.u[1] = x0.y; va.u[2] = x1.x; va.u[3] = x1.y;
    acc1 = MFMA_32x32x16_BF16(va.v, p0.v, acc1, 0, 0, 0);
    x0 = *(const uint2*)(r0 + 16);  x1 = *(const uint2*)(r0 + 24);
    va.u[0] = x0.x; va.u[1] = x0.y; va.u[2] = x1.x; va.u[3] = x1.y;
    acc0 = MFMA_32x32x16_BF16(va.v, p1.v, acc0, 0, 0, 0);
    x0 = *(const uint2*)(r1 + 16);  x1 = *(const uint2*)(r1 + 24);
    va.u[0] = x0.x; va.u[1] = x0.y; va.u[2] = x1.x; va.u[3] = x1.y;
    acc1 = MFMA_32x32x16_BF16(va.v, p1.v, acc1, 0, 0, 0);
}

// one 64-key chunk: ka from LDS, 2x (QK MFMA -> tile_pv)
__device__ __forceinline__ void chunk_body(
    const u16* __restrict__ base, const s16x8& qf, const s16x8& ones,
    int l31, int half, f32x16& acc0, f32x16& acc1, f32x16& accl)
{
    const f32x16 Z = zf16();
    s16x8 ka0 = *(const s16x8*)(base + 4608 + l31 * 8);   // keys 0..31
    s16x8 ka1 = *(const s16x8*)(base + 4864 + l31 * 8);   // keys 32..63
    {
        f32x16 Sa = MFMA_32x32x16_BF16(ka0, qf, Z, 0, 0, 0);
        tile_pv(Sa, base, l31, half, ones, acc0, acc1, accl);
    }
    {
        f32x16 Sb = MFMA_32x32x16_BF16(ka1, qf, Z, 0, 0, 0);
        tile_pv(Sb, base + 2304, l31, half, ones, acc0, acc1, accl);
    }
}

__global__ __launch_bounds__(256, 4) void k2_attn(
    const u16* __restrict__ qb, const u16* __restrict__ vt,
    u16* __restrict__ po, float* __restrict__ pl,
    int nsplit, int niter)
{
    __shared__ union SM {
        uint4 stage[4][640];                 // 4 x 10240 B chunk pipeline
        float sf[8712];                      // epilogue: 4 waves x 2178 floats
    } sm;

    const int tid  = threadIdx.x;
    const int lane = tid & 63;
    const int half = lane >> 5;
    const int l31  = lane & 31;
    const int w    = tid >> 6;               // wave 0..3
    const int qB   = (blockIdx.x % 96) * 128;
    const int sp   = blockIdx.x / 96;
    const int myq  = qB + 32 * w;            // this wave's first query
    const int key_start = sp * (NN / nsplit);
    const int ch0 = key_start >> 6;          // first 64-key chunk index

    const f32x16 Z = zf16();
    s16x8 qf = zs8();
    if (!half) qf = *(const s16x8*)(qb + (size_t)(myq + l31) * 8);

    s16x8 ones;
#pragma unroll
    for (int i = 0; i < 8; ++i) ones[i] = (short)0x3F80;   // bf16 1.0

    f32x16 acc0 = Z, acc1 = Z, accl = Z;

    // stage chunk c into buffer b: wave w covers bytes [2560w, 2560w+2560)
    // = exactly 3 vmem instructions per wave per chunk (vmcnt arithmetic).
    auto STAGE = [&](int c, int b) {
        const char* g = (const char*)vt + (size_t)(ch0 + c) * 10240
                      + 2560 * w + lane * 16;
        char* l = (char*)&sm.stage[b][0] + 2560 * w;   // wave-uniform base
        gld16(g, l);
        gld16(g + 1024, l + 1024);
        if (lane < 32) gld16(g + 2048, l + 2048);
    };

    // prologue: 3 chunks in flight (niter >= 3 always: S <= 32 -> niter >= 6)
    STAGE(0, 0);
    STAGE(1, 1);
    STAGE(2, 2);

    // main loop: steady-state wait vmcnt(6) = chunks i+1, i+2 in flight;
    // in-order retirement => chunk i fully resident.  Raw barrier (no drain).
    int it = 0;
    for (; it + 2 < niter; ++it) {
        __builtin_amdgcn_sched_barrier(0);
        __builtin_amdgcn_s_waitcnt(VMCNT(6));
        __builtin_amdgcn_s_barrier();
        __builtin_amdgcn_sched_barrier(0);
        if (it + 3 < niter) STAGE(it + 3, (it + 3) & 3);  // buf (it-1)&3, free
        chunk_body((const u16*)&sm.stage[it & 3][0], qf, ones,
                   l31, half, acc0, acc1, accl);
    }
    // tail: it = niter-2 (one chunk in flight), then it = niter-1 (none)
    __builtin_amdgcn_sched_barrier(0);
    __builtin_amdgcn_s_waitcnt(VMCNT(3));
    __builtin_amdgcn_s_barrier();
    __builtin_amdgcn_sched_barrier(0);
    chunk_body((const u16*)&sm.stage[it & 3][0], qf, ones,
               l31, half, acc0, acc1, accl);
    ++it;
    __builtin_amdgcn_sched_barrier(0);
    __builtin_amdgcn_s_waitcnt(VMCNT(0));
    __builtin_amdgcn_s_barrier();
    __builtin_amdgcn_sched_barrier(0);
    chunk_body((const u16*)&sm.stage[it & 3][0], qf, ones,
               l31, half, acc0, acc1, accl);

    // denominator: all accl rows identical = full 64-lane key-sum per query
    const float ls = accl[0];

    // ---- epilogue: ONE barrier, then per-wave private transpose scratch ----
    // sf region for wave w = sf + w*2178 (8712B); aliases the stage bufs, so
    // one barrier ensures all waves finished their last chunk_body first.
    // After that: writes and reads are same-wave LDS ops (lgkm-ordered), no
    // further barriers.  Read pattern's 2-way bank alias is free (m136).
    __syncthreads();
    float* sfw = sm.sf + w * 2178;
#pragma unroll
    for (int r = 0; r < 16; ++r) {
        const int c = (r & 3) + 8 * (r >> 2) + 4 * half;
        sfw[c * 33 + l31]        = acc0[r];
        sfw[(32 + c) * 33 + l31] = acc1[r];
    }
    if (lane < 32) sfw[2112 + l31] = ls;

    u16* poS = po + (size_t)sp * (NN * 64);
    const int lq  = lane >> 1;               // query 0..31 within wave
    const int cb0 = (lane & 1) * 32;         // channel base 0 or 32
    unsigned int u[16];
#pragma unroll
    for (int i = 0; i < 16; ++i)
        u[i] = pkbf(sfw[(cb0 + 2 * i) * 33 + lq],
                    sfw[(cb0 + 2 * i + 1) * 33 + lq]);
    u16* dst = poS + (size_t)(myq + lq) * 64 + cb0;
    *(uint4*)(dst)      = make_uint4(u[0],  u[1],  u[2],  u[3]);
    *(uint4*)(dst + 8)  = make_uint4(u[4],  u[5],  u[6],  u[7]);
    *(uint4*)(dst + 16) = make_uint4(u[8],  u[9],  u[10], u[11]);
    *(uint4*)(dst + 24) = make_uint4(u[12], u[13], u[14], u[15]);
    if (lane < 32)
        pl[(size_t)sp * NN + myq + l31] = sfw[2112 + l31];
}

// --------------------------- kernel 3: reduce splits + normalize ------------
__global__ __launch_bounds__(256) void k3_norm(
    const u16* __restrict__ po, const float* __restrict__ pl,
    float4* __restrict__ out, int nsplit)
{
    const int i = blockIdx.x * 256 + threadIdx.x;   // 196608 float4 outputs
    const int row = i >> 4;
    const int c0 = (i & 15) * 4;
    float l = 0.f;
    float o0 = 0.f, o1 = 0.f, o2 = 0.f, o3 = 0.f;
    for (int s = 0; s < nsplit; ++s) {
        l += pl[(size_t)s * NN + row];
        uint2 p = *(const uint2*)(po + (size_t)s * (NN * 64) +
                                  (size_t)row * 64 + c0);
        o0 += bf2f((u16)(p.x & 0xffff)); o1 += bf2f((u16)(p.x >> 16));
        o2 += bf2f((u16)(p.y & 0xffff)); o3 += bf2f((u16)(p.y >> 16));
    }
    const float rl = 1.0f / l;
    out[i] = make_float4(o0 * rl, o1 * rl, o2 * rl, o3 * rl);
}

// ---------------------------------------------------------------------------
extern "C" void kernel_launch(void* const* d_in, const int* in_sizes, int n_in,
                              void* d_out, int out_size, void* d_ws, size_t ws_size,
                              hipStream_t stream)
{
    const void* xmain = d_in[0];
    const void* xmod  = d_in[1];
    // d_in[2] = xyz (unused by the reference)
    const void* we1   = d_in[3];
    const void* we2   = d_in[4];
    const void* wq    = d_in[5];
    const void* wk    = d_in[6];
    const void* wv    = d_in[7];

    char* ws = (char*)d_ws;
    u16*   qb   = (u16*)  (ws + OFF_QB);
    u16*   vt   = (u16*)  (ws + OFF_VT);

    // pick the largest key-split S whose partials fit in ws (prefer 32:
    // grid 3072 = 3x1024 = 4x768, balanced at both plausible capacities)
    int S = 1;
    for (int cand = 32; cand >= 1; cand >>= 1) {
        size_t need = (size_t)OFF_PO + (size_t)cand * (NN * 64 * 2) +
                      (size_t)cand * (NN * 4);
        if (ws_size >= need) { S = cand; break; }
    }
    u16*   po = (u16*)(ws + OFF_PO);
    float* pl = (float*)(ws + OFF_PO + (size_t)S * (NN * 64 * 2));
    const int niter = NN / (64 * S);

    k1_qkv<<<192, 256, 0, stream>>>(xmain, xmod, we1, we2, wq, wk, wv,
                                    qb, vt);
    k2_attn<<<96 * S, 256, 0, stream>>>(qb, vt, po, pl, S, niter);
    k3_norm<<<768, 256, 0, stream>>>(po, pl, (float4*)d_out, S);
}

// Round 6
// 127.079 us; speedup vs baseline: 1.1067x; 1.1067x over previous
//
#include <hip/hip_runtime.h>
#include <stdint.h>

// ---------------------------------------------------------------------------
// SelfAttentiveBimodalFusion: MLP(192->16->16) -> Q(8),K(8),V(64) -> full
// N x N attention -> out (N,64).  N = 12288.  fp32 in / fp32 out.
// Validated r5-r15: absmax 9.8e-4 vs thr 2.7e-3.
//
// Ladder: r5 killed atomics, r9 global_load_lds DMA -> k2=50us, r10 query-
// split waves + bf16 partials -> 46us, r12 MFMA-ones denominator -> 44us.
// r11 FAILED (reg spill at (256,6)); r13 FAILED (128-thr crossed 128-reg
// occupancy bracket); r14 NEUTRAL (counted-vmcnt pipeline, ~43us); r15
// NEUTRAL-REGRESS (grid balance via S=32: k2 45.3us unchanged, k3 +10us).
// Cross-round invariant: k2 pinned at 44-47us from 12 to 17 waves/CU with
// ~20% per-wave issue fraction -> the block-wide barrier re-phases all
// waves every 64 keys; their dep-chain stalls are CORRELATED.  No amount
// of TLP/balance/vmcnt fixes correlated stalls.
// r16 (this): delete the synchronization.  Wave-private register staging:
//   (a) k1 stores V/K pre-swizzled in exact per-lane MFMA fragment order;
//       k2 loads operands straight into registers via coalesced
//       global_load_dwordx4 (lane*16B).  NO LDS staging, NO ds_reads,
//       NO va-assembly moves, ZERO barriers in k2 (epilogue scratch is
//       per-wave-private LDS).  One-tile-ahead named A/B register double
//       buffer hides ~200cy L2 latency under ~280cy tile compute.
//   (b) S=8 -> 768 blocks = exactly 3 blocks/CU = ONE balanced round,
//       zero tail; po partials 50->12.6MB (reclaims r15's k3 regression).
//   (c) launch_bounds(256,3): reg cap 170 (need ~140, no spill risk);
//       3 waves/SIMD is exactly the S=8 residency.
//   Cost accepted: V read 4x from L2 (737MB ~ 29TB/s < 34.5 ceiling; vt
//   is 221KB/split, resident in every XCD L2).
// ---------------------------------------------------------------------------

#define NN 12288

typedef float    f32x16 __attribute__((ext_vector_type(16)));
typedef short    s16x8  __attribute__((ext_vector_type(8)));
typedef unsigned short u16;

#define MFMA_32x32x16_BF16 __builtin_amdgcn_mfma_f32_32x32x16_bf16

// ws layout (bytes)
#define OFF_QB   0u          // N*8*2 = 196608 (bf16 Q, pre-scaled)
#define OFF_VT   196608u     // 192 chunks * 9216 B (V frags 8192 + K 1024)
#define OFF_PO   2162688u    // S*N*64*2 bf16 O partials; pl follows (S*N*4)

__device__ __forceinline__ float bf2f(u16 s) {
    union { unsigned int u; float f; } c; c.u = ((unsigned int)s) << 16; return c.f;
}
__device__ __forceinline__ u16 f2bf(float f) {
    union { float f; unsigned int u; } c; c.f = f;
    return (u16)((c.u + 0x8000u) >> 16);
}
__device__ __forceinline__ unsigned int pk2(float a, float b) {
    union { float f; unsigned int u; } ca, cb; ca.f = a; cb.f = b;
    return ((ca.u + 0x8000u) >> 16) | ((cb.u + 0x8000u) & 0xffff0000u);
}
__device__ __forceinline__ unsigned int pkbf(float a, float b) {
#if __has_builtin(__builtin_amdgcn_cvt_pk_bf16_f32)
    auto r = __builtin_amdgcn_cvt_pk_bf16_f32(a, b);
    union { decltype(r) v; unsigned int u; } c; c.v = r; return c.u;
#else
    return pk2(a, b);
#endif
}
__device__ __forceinline__ f32x16 zf16() {
    f32x16 z;
#pragma unroll
    for (int i = 0; i < 16; ++i) z[i] = 0.f;
    return z;
}
__device__ __forceinline__ s16x8 zs8() {
    s16x8 z;
#pragma unroll
    for (int i = 0; i < 8; ++i) z[i] = 0;
    return z;
}

union U8 { s16x8 v; unsigned int u[4]; };
union QV { uint4 q; s16x8 v; };

// ---------------- kernel 1: detect + weights->LDS + MLP -> Qb, Vt ----------
// Vt layout per 64-key chunk (9216 B):
//   V frags: [tile t(2)][a=chanhalf(2)][b=keyhalf(2)][lane(64)][8 u16]
//     lane = h*32 + (c&31); u16 j in frag = key offset 4h + j + 4*(j>=4)
//     (+16b +32t within chunk) of channel a*32 + (c&31)  [r5 A-frag layout]
//   K block at +8192: [key(64)][8 u16]
__global__ __launch_bounds__(256) void k1_qkv(
    const void* __restrict__ xmain, const void* __restrict__ xmod,
    const void* __restrict__ we1, const void* __restrict__ we2,
    const void* __restrict__ wqp, const void* __restrict__ wkp,
    const void* __restrict__ wvp,
    u16* __restrict__ qb, u16* __restrict__ vt)
{
    __shared__ float wf[4608];
    __shared__ int   sflag;
    __shared__ float lh1[64][4][17];
    __shared__ float lh2[64][17];

    const int t = threadIdx.x;
    const int r = t >> 2;
    const int p = t & 3;
    const int row = blockIdx.x * 64 + r;

    if (t == 0) sflag = 0;
    __syncthreads();
    {
        float v = bf2f(((const u16*)xmod)[2 * t]);
        if (fabsf(v) > 16.f) atomicAdd(&sflag, 1);
    }
    __syncthreads();
    const int isf32 = (sflag > 8);

    const float SCL = 0.51006979f;       // (1/sqrt(8)) * log2(e)
    if (isf32) {
        const float* a1 = (const float*)we1; const float* a2 = (const float*)we2;
        const float* aq = (const float*)wqp; const float* ak = (const float*)wkp;
        const float* av = (const float*)wvp;
        for (int i = t; i < 4608; i += 256) {
            if      (i < 3072) wf[i] = a1[i];
            else if (i < 3328) wf[i] = a2[i - 3072];
            else if (i < 3456) wf[i] = aq[i - 3328] * SCL;
            else if (i < 3584) wf[i] = ak[i - 3456];
            else               wf[i] = av[i - 3584];
        }
    } else {
        const u16* a1 = (const u16*)we1; const u16* a2 = (const u16*)we2;
        const u16* aq = (const u16*)wqp; const u16* ak = (const u16*)wkp;
        const u16* av = (const u16*)wvp;
        for (int i = t; i < 4608; i += 256) {
            if      (i < 3072) wf[i] = bf2f(a1[i]);
            else if (i < 3328) wf[i] = bf2f(a2[i - 3072]);
            else if (i < 3456) wf[i] = bf2f(aq[i - 3328]) * SCL;
            else if (i < 3584) wf[i] = bf2f(ak[i - 3456]);
            else               wf[i] = bf2f(av[i - 3584]);
        }
    }
    __syncthreads();

    const float* __restrict__ W1 = wf;
    const float* __restrict__ W2 = wf + 3072;
    const float* __restrict__ Wq = wf + 3328;
    const float* __restrict__ Wk = wf + 3456;
    const float* __restrict__ Wv = wf + 3584;

    float h1p[16];
#pragma unroll
    for (int o = 0; o < 16; ++o) h1p[o] = 0.f;

    if (isf32) {
#pragma unroll
        for (int cc = 0; cc < 12; ++cc) {
            const int c = p + cc * 4;
            float4 xv = (c < 16)
                ? ((const float4*)xmain)[(size_t)row * 16 + c]
                : ((const float4*)xmod)[(size_t)row * 32 + (c - 16)];
            float xs[4] = {xv.x, xv.y, xv.z, xv.w};
#pragma unroll
            for (int j = 0; j < 4; ++j) {
                const float* wr = W1 + (c * 4 + j) * 16;
#pragma unroll
                for (int o = 0; o < 16; ++o) h1p[o] += xs[j] * wr[o];
            }
        }
    } else {
#pragma unroll
        for (int cc = 0; cc < 12; ++cc) {
            const int c = p + cc * 4;
            uint2 xv = (c < 16)
                ? ((const uint2*)xmain)[(size_t)row * 16 + c]
                : ((const uint2*)xmod)[(size_t)row * 32 + (c - 16)];
            float xs[4] = { bf2f((u16)(xv.x & 0xffff)), bf2f((u16)(xv.x >> 16)),
                            bf2f((u16)(xv.y & 0xffff)), bf2f((u16)(xv.y >> 16)) };
#pragma unroll
            for (int j = 0; j < 4; ++j) {
                const float* wr = W1 + (c * 4 + j) * 16;
#pragma unroll
                for (int o = 0; o < 16; ++o) h1p[o] += xs[j] * wr[o];
            }
        }
    }
#pragma unroll
    for (int o = 0; o < 16; ++o) lh1[r][p][o] = h1p[o];
    __syncthreads();

    float h1[16];
#pragma unroll
    for (int o = 0; o < 16; ++o)
        h1[o] = fmaxf(lh1[r][0][o] + lh1[r][1][o] + lh1[r][2][o] + lh1[r][3][o], 0.f);

#pragma unroll
    for (int oo = 0; oo < 4; ++oo) {
        const int o = p * 4 + oo;
        float s = 0.f;
#pragma unroll
        for (int j = 0; j < 16; ++j) s += h1[j] * W2[j * 16 + o];
        lh2[r][o] = fmaxf(s, 0.f);
    }
    __syncthreads();

    float h2[16];
#pragma unroll
    for (int j = 0; j < 16; ++j) h2[j] = lh2[r][j];

    {
        float q0 = 0.f, q1 = 0.f, k0 = 0.f, k1 = 0.f;
        const int o = 2 * p;
#pragma unroll
        for (int j = 0; j < 16; ++j) {
            q0 += h2[j] * Wq[j * 8 + o];
            q1 += h2[j] * Wq[j * 8 + o + 1];
            k0 += h2[j] * Wk[j * 8 + o];
            k1 += h2[j] * Wk[j * 8 + o + 1];
        }
        ((unsigned int*)qb)[(size_t)row * 4 + p] = pk2(q0, q1);
        // K block: chunk*2304 u32, base 2048 u32, [key&63][word p]
        ((unsigned int*)vt)[(size_t)(row >> 6) * 2304 + 2048 +
                            (row & 63) * 4 + p] = pk2(k0, k1);
    }

    // V store into fragment-native layout (see header comment)
    {
        const int ch = row >> 6, tI = (row >> 5) & 1, kk = row & 31;
        const int b   = kk >> 4, kk4 = kk & 15;
        const int hh  = (kk4 >> 2) & 1;
        const int jj  = (kk4 & 3) + 4 * (kk4 >> 3);
        const size_t cbase = (size_t)ch * 4608 + (size_t)(tI * 4 + b) * 512
                           + hh * 256 + jj;
#pragma unroll
        for (int c16 = 0; c16 < 16; ++c16) {
            const int c = p * 16 + c16;
            float v = 0.f;
#pragma unroll
            for (int j = 0; j < 16; ++j) v += h2[j] * Wv[j * 64 + c];
            vt[cbase + (size_t)(c >> 5) * 1024 + (c & 31) * 8] = f2bf(v);
        }
    }
}

// --------------------------- kernel 2: attention partials -------------------
// grid = 96 q-blocks * S=8 key-splits = 768 blocks = exactly 3 blocks/CU,
// ONE balanced round.  block = 256 thr = 4 waves x 32q, but waves are fully
// independent: operands loaded straight into registers from the fragment-
// native vt (coalesced dwordx4), per-wave-private epilogue LDS, ZERO
// barriers.  Named A/B register double buffer = one-tile-ahead prefetch.
// launch_bounds(256,3): reg cap 170 (need ~140; r11/r13 lessons).

__global__ __launch_bounds__(256, 3) void k2_attn(
    const u16* __restrict__ qb, const u16* __restrict__ vt,
    u16* __restrict__ po, float* __restrict__ pl,
    int nsplit, int ntile)
{
    __shared__ float sf[4][2178];            // per-wave private scratch

    const int tid  = threadIdx.x;
    const int lane = tid & 63;
    const int half = lane >> 5;
    const int l31  = lane & 31;
    const int w    = tid >> 6;               // wave 0..3
    const int qB   = (blockIdx.x % 96) * 128;
    const int sp   = blockIdx.x / 96;
    const int myq  = qB + 32 * w;
    const int key_start = sp * (NN / nsplit);
    const char* vbase = (const char*)vt + (size_t)(key_start >> 6) * 9216;

    const f32x16 Z = zf16();
    s16x8 qf = zs8();
    if (!half) qf = *(const s16x8*)(qb + (size_t)(myq + l31) * 8);

    s16x8 ones;
#pragma unroll
    for (int i = 0; i < 8; ++i) ones[i] = (short)0x3F80;   // bf16 1.0

    f32x16 acc0 = Z, acc1 = Z, accl = Z;

    QV kaA, f00A, f10A, f01A, f11A;
    QV kaB, f00B, f10B, f01B, f11B;

    // load one 32-key tile's operands (5 coalesced dwordx4 per lane)
#define LDT(gt, ka, f00, f10, f01, f11) do {                                  \
    const char* cb_ = vbase + (size_t)((gt) >> 1) * 9216 + ((gt) & 1) * 4096; \
    (f00).q = *(const uint4*)(cb_ +        lane * 16);                        \
    (f01).q = *(const uint4*)(cb_ + 1024 + lane * 16);                        \
    (f10).q = *(const uint4*)(cb_ + 2048 + lane * 16);                        \
    (f11).q = *(const uint4*)(cb_ + 3072 + lane * 16);                        \
    (ka).q  = *(const uint4*)(vbase + (size_t)((gt) >> 1) * 9216 + 8192       \
                              + ((gt) & 1) * 512 + l31 * 16);                 \
} while (0)

    // one 32-key tile: QK MFMA -> exp -> pack -> l-sum MFMA -> 4 PV MFMAs
#define TILE(ka, f00, f10, f01, f11) do {                                     \
    f32x16 S_ = MFMA_32x32x16_BF16((ka).v, qf, Z, 0, 0, 0);                   \
    float pr_[16];                                                            \
    _Pragma("unroll")                                                         \
    for (int r_ = 0; r_ < 16; ++r_) pr_[r_] = __builtin_amdgcn_exp2f(S_[r_]); \
    U8 p0_, p1_;                                                              \
    _Pragma("unroll")                                                         \
    for (int i_ = 0; i_ < 4; ++i_) {                                          \
        p0_.u[i_] = pkbf(pr_[2 * i_],     pr_[2 * i_ + 1]);                   \
        p1_.u[i_] = pkbf(pr_[8 + 2 * i_], pr_[8 + 2 * i_ + 1]);               \
    }                                                                         \
    accl = MFMA_32x32x16_BF16(ones, p0_.v, accl, 0, 0, 0);                    \
    accl = MFMA_32x32x16_BF16(ones, p1_.v, accl, 0, 0, 0);                    \
    acc0 = MFMA_32x32x16_BF16((f00).v, p0_.v, acc0, 0, 0, 0);                 \
    acc1 = MFMA_32x32x16_BF16((f10).v, p0_.v, acc1, 0, 0, 0);                 \
    acc0 = MFMA_32x32x16_BF16((f01).v, p1_.v, acc0, 0, 0, 0);                 \
    acc1 = MFMA_32x32x16_BF16((f11).v, p1_.v, acc1, 0, 0, 0);                 \
} while (0)

    LDT(0, kaA, f00A, f10A, f01A, f11A);
    int gt = 0;
    for (; gt + 2 < ntile; gt += 2) {
        LDT(gt + 1, kaB, f00B, f10B, f01B, f11B);
        TILE(kaA, f00A, f10A, f01A, f11A);
        LDT(gt + 2, kaA, f00A, f10A, f01A, f11A);
        TILE(kaB, f00B, f10B, f01B, f11B);
    }
    LDT(gt + 1, kaB, f00B, f10B, f01B, f11B);
    TILE(kaA, f00A, f10A, f01A, f11A);
    TILE(kaB, f00B, f10B, f01B, f11B);

#undef LDT
#undef TILE

    // denominator: all accl rows identical = full 64-lane key-sum per query
    const float ls = accl[0];

    // ---- epilogue: per-wave PRIVATE transpose scratch, zero barriers ------
    float* sfw = &sf[w][0];
#pragma unroll
    for (int r = 0; r < 16; ++r) {
        const int c = (r & 3) + 8 * (r >> 2) + 4 * half;
        sfw[c * 33 + l31]        = acc0[r];
        sfw[(32 + c) * 33 + l31] = acc1[r];
    }
    if (lane < 32) sfw[2112 + l31] = ls;

    u16* poS = po + (size_t)sp * (NN * 64);
    const int lq  = lane >> 1;               // query 0..31 within wave
    const int cb0 = (lane & 1) * 32;         // channel base 0 or 32
    unsigned int u[16];
#pragma unroll
    for (int i = 0; i < 16; ++i)
        u[i] = pkbf(sfw[(cb0 + 2 * i) * 33 + lq],
                    sfw[(cb0 + 2 * i + 1) * 33 + lq]);
    u16* dst = poS + (size_t)(myq + lq) * 64 + cb0;
    *(uint4*)(dst)      = make_uint4(u[0],  u[1],  u[2],  u[3]);
    *(uint4*)(dst + 8)  = make_uint4(u[4],  u[5],  u[6],  u[7]);
    *(uint4*)(dst + 16) = make_uint4(u[8],  u[9],  u[10], u[11]);
    *(uint4*)(dst + 24) = make_uint4(u[12], u[13], u[14], u[15]);
    if (lane < 32)
        pl[(size_t)sp * NN + myq + l31] = sfw[2112 + l31];
}

// --------------------------- kernel 3: reduce splits + normalize ------------
__global__ __launch_bounds__(256) void k3_norm(
    const u16* __restrict__ po, const float* __restrict__ pl,
    float4* __restrict__ out, int nsplit)
{
    const int i = blockIdx.x * 256 + threadIdx.x;   // 196608 float4 outputs
    const int row = i >> 4;
    const int c0 = (i & 15) * 4;
    float l = 0.f;
    float o0 = 0.f, o1 = 0.f, o2 = 0.f, o3 = 0.f;
    for (int s = 0; s < nsplit; ++s) {
        l += pl[(size_t)s * NN + row];
        uint2 p = *(const uint2*)(po + (size_t)s * (NN * 64) +
                                  (size_t)row * 64 + c0);
        o0 += bf2f((u16)(p.x & 0xffff)); o1 += bf2f((u16)(p.x >> 16));
        o2 += bf2f((u16)(p.y & 0xffff)); o3 += bf2f((u16)(p.y >> 16));
    }
    const float rl = 1.0f / l;
    out[i] = make_float4(o0 * rl, o1 * rl, o2 * rl, o3 * rl);
}

// ---------------------------------------------------------------------------
extern "C" void kernel_launch(void* const* d_in, const int* in_sizes, int n_in,
                              void* d_out, int out_size, void* d_ws, size_t ws_size,
                              hipStream_t stream)
{
    const void* xmain = d_in[0];
    const void* xmod  = d_in[1];
    // d_in[2] = xyz (unused by the reference)
    const void* we1   = d_in[3];
    const void* we2   = d_in[4];
    const void* wq    = d_in[5];
    const void* wk    = d_in[6];
    const void* wv    = d_in[7];

    char* ws = (char*)d_ws;
    u16*   qb   = (u16*)  (ws + OFF_QB);
    u16*   vt   = (u16*)  (ws + OFF_VT);

    // S = 8: grid 768 = exactly 3 blocks/CU, one balanced round, minimal
    // partial traffic.  Fallback halving only if ws is unexpectedly small.
    int S = 8;
    while (S > 1) {
        size_t need = (size_t)OFF_PO + (size_t)S * (NN * 64 * 2) +
                      (size_t)S * (NN * 4);
        if (ws_size >= need) break;
        S >>= 1;
    }
    u16*   po = (u16*)(ws + OFF_PO);
    float* pl = (float*)(ws + OFF_PO + (size_t)S * (NN * 64 * 2));
    const int ntile = NN / (32 * S);

    k1_qkv<<<192, 256, 0, stream>>>(xmain, xmod, we1, we2, wq, wk, wv,
                                    qb, vt);
    k2_attn<<<96 * S, 256, 0, stream>>>(qb, vt, po, pl, S, ntile);
    k3_norm<<<768, 256, 0, stream>>>(po, pl, (float4*)d_out, S);
}